// Round 6
// baseline (795.101 us; speedup 1.0000x reference)
//
#include <hip/hip_runtime.h>
#include <math.h>

#define NHEADS 6
#define CC 192
#define HDIM 32
#define NTOK 256
#define SHIFTV 8

typedef __attribute__((ext_vector_type(8))) short short8;   // 8 x bf16
typedef __attribute__((ext_vector_type(4))) short short4v;  // 4 x bf16
typedef __attribute__((ext_vector_type(4))) float floatx4;

__device__ inline short f2bf(float f) {
    union { float f; unsigned u; } v; v.f = f;
    unsigned r = (v.u + 0x7FFFu + ((v.u >> 16) & 1u)) >> 16;
    return (short)r;
}

// tanh-form GELU as x*sigmoid(2u), u = 0.7978845608(x + 0.044715 x^3).
__device__ inline float gelu_f(float x) {
    float x2 = x * x;
    float p = x * (-1.5957691216f - 0.07135481627f * x2);   // = -2u
    float e = __expf(p);
    return x * __builtin_amdgcn_rcpf(1.f + e);
}

// ---------------- bias gather (natural layout): biasB[h][n][m] = rpb[rpi[n][m]][h] ----------------
__global__ __launch_bounds__(256) void bias_kernel(const int* __restrict__ rpi,
                                                   const float* __restrict__ rpb,
                                                   float* __restrict__ biasB) {
    int idx = blockIdx.x * 256 + threadIdx.x;   // idx = h*65536 + n*256 + m
    int m = idx & 255;
    int n = (idx >> 8) & 255;
    int h = idx >> 16;
    biasB[idx] = rpb[rpi[n * 256 + m] * NHEADS + h];
}

// ---------------- weight convert/transpose to bf16 for MFMA B-fragments ----------------
// WQT[n][k] 576x192, PWT[c][k] 192x192, W1T[n][k] 768x192, W2T[c][h] 192x768
__global__ __launch_bounds__(256) void cvt_kernel(const float* __restrict__ qkvw,
                                                  const float* __restrict__ pw,
                                                  const float* __restrict__ f1w,
                                                  const float* __restrict__ f2w,
                                                  short* __restrict__ wqt,
                                                  short* __restrict__ pwt,
                                                  short* __restrict__ w1t,
                                                  short* __restrict__ w2t) {
    int idx = blockIdx.x * 256 + threadIdx.x;   // 147456 total
    int n = idx / 192, k = idx - n * 192;
    w1t[idx] = f2bf(f1w[k * 768 + n]);
    int c = idx / 768, h = idx - c * 768;
    w2t[idx] = f2bf(f2w[h * 192 + c]);
    if (idx < 576 * 192) wqt[idx] = f2bf(qkvw[k * 576 + n]);
    if (idx < 192 * 192) pwt[idx] = f2bf(pw[k * 192 + n]);
}

// ---------------- MFMA fused LN1 + shifted-window gather + QKV GEMM ----------------
__global__ __launch_bounds__(256) void qkv_kernel(const float* __restrict__ x,
        const float* __restrict__ g1, const float* __restrict__ b1,
        const short* __restrict__ wqt, const float* __restrict__ qkvb,
        ushort* __restrict__ Qb, ushort* __restrict__ Kb, ushort* __restrict__ VTb) {
    __shared__ __align__(16) short xln[64 * 200];   // bf16 A-tile, stride 200
    __shared__ float red[64][4][2];
    const int t = threadIdx.x;
    const int g0 = blockIdx.x * 64;
    const int w = g0 >> 8;
    {
        int row = t >> 2, part = t & 3;
        int n = (g0 + row) & 255;
        int sy = (((w >> 4) << 4) + (n >> 4) + SHIFTV) & 255;
        int sx = (((w & 15) << 4) + (n & 15) + SHIFTV) & 255;
        const float* xr = x + (sy * 256 + sx) * CC + part * 48;
        float vals[48];
        float s = 0.f, ss = 0.f;
        #pragma unroll
        for (int i = 0; i < 48; ++i) { float v = xr[i]; vals[i] = v; s += v; ss += v * v; }
        red[row][part][0] = s; red[row][part][1] = ss;
        __syncthreads();
        float sum = red[row][0][0] + red[row][1][0] + red[row][2][0] + red[row][3][0];
        float sq  = red[row][0][1] + red[row][1][1] + red[row][2][1] + red[row][3][1];
        float mean = sum * (1.f / 192.f);
        float var = sq * (1.f / 192.f) - mean * mean;
        float inv = rsqrtf(var + 1e-5f);
        #pragma unroll
        for (int i = 0; i < 48; ++i) {
            int c = part * 48 + i;
            xln[row * 200 + c] = f2bf((vals[i] - mean) * inv * g1[c] + b1[c]);
        }
    }
    __syncthreads();
    const int wv = t >> 6, lane = t & 63;
    const int lr = lane & 15;
    const int lk = (lane >> 4) * 8;
    const int q4 = (lane >> 4) * 4;
    #pragma unroll
    for (int jc = 0; jc < 3; ++jc) {            // jc: 0=Q, 1=K, 2=V (192 cols each)
        floatx4 acc[4][3];
        #pragma unroll
        for (int mt = 0; mt < 4; ++mt)
            #pragma unroll
            for (int nt = 0; nt < 3; ++nt) acc[mt][nt] = floatx4{0.f,0.f,0.f,0.f};
        for (int ks = 0; ks < 6; ++ks) {
            int k0 = ks * 32 + lk;
            short8 a[4];
            #pragma unroll
            for (int mt = 0; mt < 4; ++mt)
                a[mt] = *(const short8*)&xln[(mt * 16 + lr) * 200 + k0];
            #pragma unroll
            for (int nt = 0; nt < 3; ++nt) {
                int nglob = jc * 192 + wv * 48 + nt * 16 + lr;
                short8 b = *(const short8*)&wqt[nglob * 192 + k0];
                #pragma unroll
                for (int mt = 0; mt < 4; ++mt)
                    acc[mt][nt] = __builtin_amdgcn_mfma_f32_16x16x32_bf16(a[mt], b, acc[mt][nt], 0, 0, 0);
            }
        }
        #pragma unroll
        for (int nt = 0; nt < 3; ++nt) {
            int jj = wv * 48 + nt * 16 + lr;      // 0..191 within section
            float bias = qkvb[jc * 192 + jj];
            int head = jj >> 5, hd = jj & 31;
            int wh = w * NHEADS + head;
            #pragma unroll
            for (int mt = 0; mt < 4; ++mt) {
                int nr0 = (g0 + mt * 16 + q4) & 255;
                if (jc == 0) {
                    #pragma unroll
                    for (int reg = 0; reg < 4; ++reg)
                        Qb[((size_t)wh * NTOK + nr0 + reg) * HDIM + hd] =
                            (ushort)f2bf((acc[mt][nt][reg] + bias) * 0.17677669529663687f);
                } else if (jc == 1) {
                    #pragma unroll
                    for (int reg = 0; reg < 4; ++reg)
                        Kb[((size_t)wh * NTOK + nr0 + reg) * HDIM + hd] =
                            (ushort)f2bf(acc[mt][nt][reg] + bias);
                } else {
                    short4v pk;
                    #pragma unroll
                    for (int reg = 0; reg < 4; ++reg)
                        pk[reg] = f2bf(acc[mt][nt][reg] + bias);
                    *(short4v*)&VTb[((size_t)wh * HDIM + hd) * NTOK + nr0] = pk;
                }
            }
        }
    }
}

// ---------------- MFMA flash attention, straight-exp softmax ----------------
__global__ __launch_bounds__(256) void attn_kernel(const ushort* __restrict__ Q,
        const ushort* __restrict__ K, const ushort* __restrict__ VT,
        const float* __restrict__ biasB, const float* __restrict__ mask,
        ushort* __restrict__ Ob) {
    __shared__ __align__(16) ushort Ks[256 * 40];    // [key][hd], stride 40
    __shared__ __align__(16) ushort Vs[32 * 264];    // [hd][key], stride 264
    __shared__ __align__(16) ushort Ps[4][64 * 40];  // per-wave P^T chunk [q][m], stride 40
    const int t = threadIdx.x;
    const int wh = blockIdx.x;
    const int w = wh / 6, h = wh - w * 6;
    {
        const ushort* kg = K + (size_t)wh * (NTOK * HDIM);
        const ushort* vg = VT + (size_t)wh * (NTOK * HDIM);
        for (int i = t * 8; i < NTOK * HDIM; i += 2048) {
            short8 kv = *(const short8*)(kg + i);
            *(short8*)&Ks[(i >> 5) * 40 + (i & 31)] = kv;
            short8 vv = *(const short8*)(vg + i);
            *(short8*)&Vs[(i >> 8) * 264 + (i & 255)] = vv;
        }
    }
    const int wv = t >> 6, lane = t & 63;
    const int lc = lane & 15;
    const int q4 = (lane >> 4) * 4;
    const int lk8 = (lane >> 4) * 8;
    const int qb = wv * 64;
    short8 qf[4];
    {
        const ushort* qg = Q + (size_t)wh * (NTOK * HDIM);
        #pragma unroll
        for (int qt = 0; qt < 4; ++qt)
            qf[qt] = *(const short8*)(qg + (qb + qt * 16 + lc) * HDIM + lk8);
    }
    __syncthreads();
    float Ssum[4];
    floatx4 o[2][4];
    #pragma unroll
    for (int qt = 0; qt < 4; ++qt) {
        Ssum[qt] = 0.f;
        o[0][qt] = floatx4{0.f,0.f,0.f,0.f};
        o[1][qt] = floatx4{0.f,0.f,0.f,0.f};
    }
    ushort* Pw = &Ps[wv][0];
    const float* bp = biasB + h * 65536;
    const float* mp = mask + (size_t)w * 65536;
    for (int kc = 0; kc < 8; ++kc) {
        const int k0 = kc * 32;
        short8 ka[2];
        ka[0] = *(const short8*)&Ks[(k0 + lc) * 40 + lk8];
        ka[1] = *(const short8*)&Ks[(k0 + 16 + lc) * 40 + lk8];
        floatx4 sf[2][4];
        #pragma unroll
        for (int kt = 0; kt < 2; ++kt)
            #pragma unroll
            for (int qt = 0; qt < 4; ++qt)
                sf[kt][qt] = __builtin_amdgcn_mfma_f32_16x16x32_bf16(ka[kt], qf[qt],
                                floatx4{0.f,0.f,0.f,0.f}, 0, 0, 0);
        #pragma unroll
        for (int kt = 0; kt < 2; ++kt)
            #pragma unroll
            for (int qt = 0; qt < 4; ++qt) {
                int q = qb + qt * 16 + lc;
                int kbase = k0 + kt * 16 + q4;
                float4 bb = *(const float4*)(bp + q * 256 + kbase);
                float4 mm = *(const float4*)(mp + q * 256 + kbase);
                float p0 = __expf(sf[kt][qt][0] + bb.x + mm.x);
                float p1 = __expf(sf[kt][qt][1] + bb.y + mm.y);
                float p2 = __expf(sf[kt][qt][2] + bb.z + mm.z);
                float p3 = __expf(sf[kt][qt][3] + bb.w + mm.w);
                Ssum[qt] += (p0 + p1) + (p2 + p3);
                short4v pk;
                pk.x = f2bf(p0); pk.y = f2bf(p1); pk.z = f2bf(p2); pk.w = f2bf(p3);
                *(short4v*)&Pw[(qt * 16 + lc) * 40 + kt * 16 + q4] = pk;
            }
        short8 va[2], pf[4];
        va[0] = *(const short8*)&Vs[lc * 264 + k0 + lk8];
        va[1] = *(const short8*)&Vs[(16 + lc) * 264 + k0 + lk8];
        #pragma unroll
        for (int qt = 0; qt < 4; ++qt)
            pf[qt] = *(const short8*)&Pw[(qt * 16 + lc) * 40 + lk8];
        #pragma unroll
        for (int ht = 0; ht < 2; ++ht)
            #pragma unroll
            for (int qt = 0; qt < 4; ++qt)
                o[ht][qt] = __builtin_amdgcn_mfma_f32_16x16x32_bf16(va[ht], pf[qt], o[ht][qt], 0, 0, 0);
    }
    #pragma unroll
    for (int qt = 0; qt < 4; ++qt) {
        float rs = Ssum[qt];
        rs += __shfl_xor(rs, 16);
        rs += __shfl_xor(rs, 32);
        float inv = 1.f / rs;
        size_t rowbase = ((size_t)(w * NTOK + qb + qt * 16 + lc)) * CC + h * HDIM;
        #pragma unroll
        for (int ht = 0; ht < 2; ++ht)
            #pragma unroll
            for (int r = 0; r < 4; ++r)
                Ob[rowbase + ht * 16 + q4 + r] = (ushort)f2bf(o[ht][qt][r] * inv);
    }
}

// ---------------- MFMA proj GEMM + window reverse/unshift + residual(x) ----------------
__global__ __launch_bounds__(256) void proj_kernel(const ushort* __restrict__ Ob,
        const short* __restrict__ pwt, const float* __restrict__ pb,
        const float* __restrict__ x, float* __restrict__ out) {
    __shared__ __align__(16) short oln[64 * 200];
    const int t = threadIdx.x;
    const int g0 = blockIdx.x * 64;
    const int w = g0 >> 8;
    {
        int row = t >> 2, part = t & 3;
        const ushort* orow = Ob + (size_t)(g0 + row) * CC + part * 48;
        #pragma unroll
        for (int i = 0; i < 6; ++i)
            *(short8*)&oln[row * 200 + part * 48 + i * 8] = *(const short8*)(orow + i * 8);
    }
    __syncthreads();
    const int wv = t >> 6, lane = t & 63;
    const int lr = lane & 15;
    const int lk = (lane >> 4) * 8;
    const int q4 = (lane >> 4) * 4;
    floatx4 acc[4][3];
    #pragma unroll
    for (int mt = 0; mt < 4; ++mt)
        #pragma unroll
        for (int nt = 0; nt < 3; ++nt) acc[mt][nt] = floatx4{0.f,0.f,0.f,0.f};
    for (int ks = 0; ks < 6; ++ks) {
        int k0 = ks * 32 + lk;
        short8 a[4];
        #pragma unroll
        for (int mt = 0; mt < 4; ++mt)
            a[mt] = *(const short8*)&oln[(mt * 16 + lr) * 200 + k0];
        #pragma unroll
        for (int nt = 0; nt < 3; ++nt) {
            int c = wv * 48 + nt * 16 + lr;
            short8 b = *(const short8*)&pwt[c * 192 + k0];
            #pragma unroll
            for (int mt = 0; mt < 4; ++mt)
                acc[mt][nt] = __builtin_amdgcn_mfma_f32_16x16x32_bf16(a[mt], b, acc[mt][nt], 0, 0, 0);
        }
    }
    #pragma unroll
    for (int nt = 0; nt < 3; ++nt) {
        int c = wv * 48 + nt * 16 + lr;
        float bias = pb[c];
        #pragma unroll
        for (int mt = 0; mt < 4; ++mt) {
            #pragma unroll
            for (int reg = 0; reg < 4; ++reg) {
                int nn = (g0 + mt * 16 + q4 + reg) & 255;
                int sy = (((w >> 4) << 4) + (nn >> 4) + SHIFTV) & 255;
                int sx = (((w & 15) << 4) + (nn & 15) + SHIFTV) & 255;
                size_t base = (size_t)(sy * 256 + sx) * CC;
                out[base + c] = x[base + c] + acc[mt][nt][reg] + bias;
            }
        }
    }
}

// ---------------- Barrier-free MFMA MLP: each wave owns 16 rows end-to-end ----------------
// No __syncthreads anywhere: LN stats via xor-shuffles; xln/Hs are per-wave
// LDS slices (wave-internal write->read, compiler lgkmcnt handles ordering,
// validated by attn's Ps round-trip). Waves slip freely -> cross-wave overlap.
__global__ __launch_bounds__(256) void mlp_kernel(const float* __restrict__ g2,
        const float* __restrict__ b2, const short* __restrict__ w1t,
        const float* __restrict__ f1b, const short* __restrict__ w2t,
        const float* __restrict__ f2b, float* __restrict__ out) {
    __shared__ __align__(16) short xln[4][16 * 200];  // per-wave LN'd rows (bf16)
    __shared__ __align__(16) short Hs[4][16 * 200];   // per-wave GELU'd hidden chunk
    const int t = threadIdx.x;
    const int wv = t >> 6, lane = t & 63;
    const int lr = lane & 15;                 // row within wave tile / B col within tile
    const int lk = (lane >> 4) * 8;           // k-offset in A/B fragments
    const int q4 = (lane >> 4) * 4;           // C/D row base
    const int m0 = blockIdx.x * 64 + wv * 16; // this wave's first global row
    short* xw = &xln[wv][0];
    short* hw = &Hs[wv][0];
    // ---- LN2 (per-wave): lane handles row lr, cols [part*48, part*48+48) ----
    {
        int part = lane >> 4;
        const float* xr = out + (size_t)(m0 + lr) * CC + part * 48;
        float vals[48];
        float s = 0.f, ss = 0.f;
        #pragma unroll
        for (int i = 0; i < 48; ++i) { float v = xr[i]; vals[i] = v; s += v; ss += v * v; }
        s += __shfl_xor(s, 16);  ss += __shfl_xor(ss, 16);
        s += __shfl_xor(s, 32);  ss += __shfl_xor(ss, 32);
        float mean = s * (1.f / 192.f);
        float var = ss * (1.f / 192.f) - mean * mean;
        float inv = rsqrtf(var + 1e-5f);
        #pragma unroll
        for (int i = 0; i < 48; ++i) {
            int c = part * 48 + i;
            xw[lr * 200 + c] = f2bf((vals[i] - mean) * inv * g2[c] + b2[c]);
        }
    }
    floatx4 acc2[12];
    #pragma unroll
    for (int nt = 0; nt < 12; ++nt) acc2[nt] = floatx4{0.f, 0.f, 0.f, 0.f};

    for (int hc = 0; hc < 4; ++hc) {
        // ---- fc1: own 16 rows x 192 chunk cols ----
        floatx4 acc1[12];
        #pragma unroll
        for (int nt = 0; nt < 12; ++nt) acc1[nt] = floatx4{0.f, 0.f, 0.f, 0.f};
        for (int ks = 0; ks < 6; ++ks) {
            int k0 = ks * 32 + lk;
            short8 a = *(const short8*)&xw[lr * 200 + k0];
            #pragma unroll
            for (int ng = 0; ng < 3; ++ng) {          // nt groups of 4 (cap live b regs)
                #pragma unroll
                for (int nj = 0; nj < 4; ++nj) {
                    int nt = ng * 4 + nj;
                    int n = hc * 192 + nt * 16 + lr;
                    short8 b = *(const short8*)&w1t[n * 192 + k0];
                    acc1[nt] = __builtin_amdgcn_mfma_f32_16x16x32_bf16(a, b, acc1[nt], 0, 0, 0);
                }
            }
        }
        // ---- bias + GELU -> per-wave Hs ----
        #pragma unroll
        for (int nt = 0; nt < 12; ++nt) {
            int colb = nt * 16 + lr;
            float bias = f1b[hc * 192 + colb];
            #pragma unroll
            for (int reg = 0; reg < 4; ++reg) {
                float v = acc1[nt][reg] + bias;
                hw[(q4 + reg) * 200 + colb] = f2bf(gelu_f(v));
            }
        }
        // ---- fc2 accumulate over this chunk's 192 hiddens ----
        for (int ks = 0; ks < 6; ++ks) {
            int k0 = ks * 32 + lk;
            short8 a = *(const short8*)&hw[lr * 200 + k0];
            #pragma unroll
            for (int ng = 0; ng < 3; ++ng) {
                #pragma unroll
                for (int nj = 0; nj < 4; ++nj) {
                    int nt = ng * 4 + nj;
                    int c = nt * 16 + lr;
                    short8 b = *(const short8*)&w2t[c * 768 + hc * 192 + k0];
                    acc2[nt] = __builtin_amdgcn_mfma_f32_16x16x32_bf16(a, b, acc2[nt], 0, 0, 0);
                }
            }
        }
    }
    // ---- epilogue: + f2b + residual ----
    #pragma unroll
    for (int nt = 0; nt < 12; ++nt) {
        int c = nt * 16 + lr;
        float bias = f2b[c];
        #pragma unroll
        for (int reg = 0; reg < 4; ++reg) {
            size_t off = (size_t)(m0 + q4 + reg) * CC + c;
            out[off] = out[off] + acc2[nt][reg] + bias;
        }
    }
}

extern "C" void kernel_launch(void* const* d_in, const int* in_sizes, int n_in,
                              void* d_out, int out_size, void* d_ws, size_t ws_size,
                              hipStream_t stream) {
    (void)in_sizes; (void)n_in; (void)out_size; (void)ws_size;
    const float* x    = (const float*)d_in[0];
    const int*   rpi  = (const int*)d_in[1];
    const float* mask = (const float*)d_in[2];
    const float* n1g  = (const float*)d_in[3];
    const float* n1b  = (const float*)d_in[4];
    const float* qkvw = (const float*)d_in[5];
    const float* qkvb = (const float*)d_in[6];
    const float* rpb  = (const float*)d_in[7];
    const float* pw   = (const float*)d_in[8];
    const float* pb   = (const float*)d_in[9];
    const float* n2g  = (const float*)d_in[10];
    const float* n2b  = (const float*)d_in[11];
    const float* f1w  = (const float*)d_in[12];
    const float* f1b  = (const float*)d_in[13];
    const float* f2w  = (const float*)d_in[14];
    const float* f2b  = (const float*)d_in[15];
    float* out = (float*)d_out;

    ushort* Qb  = (ushort*)d_ws;            // 12,582,912 bf16 each
    ushort* Kb  = Qb + 12582912;
    ushort* VTb = Kb + 12582912;
    ushort* Ob  = VTb + 12582912;
    float* BIAS = (float*)(Ob + 12582912);  // 393,216 floats
    short* WQT  = (short*)(BIAS + 393216);  // 110,592 bf16
    short* PWT  = WQT + 110592;             // 36,864 bf16
    short* W1T  = PWT + 36864;              // 147,456 bf16
    short* W2T  = W1T + 147456;             // 147,456 bf16

    bias_kernel<<<1536, 256, 0, stream>>>(rpi, rpb, BIAS);
    cvt_kernel<<<576, 256, 0, stream>>>(qkvw, pw, f1w, f2w, WQT, PWT, W1T, W2T);
    qkv_kernel<<<1024, 256, 0, stream>>>(x, n1g, n1b, WQT, qkvb, Qb, Kb, VTb);
    attn_kernel<<<1536, 256, 0, stream>>>(Qb, Kb, VTb, BIAS, mask, Ob);
    proj_kernel<<<1024, 256, 0, stream>>>(Ob, PWT, pb, x, out);
    mlp_kernel<<<1024, 256, 0, stream>>>(n2g, n2b, W1T, f1b, W2T, f2b, out);
}